// Round 6
// baseline (634.519 us; speedup 1.0000x reference)
//
#include <hip/hip_runtime.h>
#include <hip/hip_bf16.h>

// NARX RNN. Inputs fp32, compute bf16 MFMA 16x16x32, output fp32.
// Transposed GEMMs (Ht[n][m] = W^T . act^T): weight A-frags hoisted to regs,
// C/D output packs straight into the [m][hid] LDS layout the next B-frag
// read wants. LDS row stride 72 shorts (144B), rows 16B-aligned for b128.
// Main-loop LDS is wave-private -> NO __syncthreads in the hot loop.
// __launch_bounds__(256,4): R4/R5 showed occupancy pinned at ~2 blocks/CU
// with (256,2); demand 4 waves/EU (VGPR<=128) to unlock 4 blocks/CU.

#define NTT   512
#define NG    2048
#define NXF   16
#define HIDN  64
#define DLAG  4
#define TOUTN 508
#define GBLK  128   // g rows per block (4 waves x 32)
#define TTB   4     // tt values per block
#define STR   72    // LDS row stride in shorts

typedef short  short8 __attribute__((ext_vector_type(8)));
typedef float  f32x4  __attribute__((ext_vector_type(4)));
typedef int    i32x4  __attribute__((ext_vector_type(4)));
typedef unsigned int u32x2 __attribute__((ext_vector_type(2)));

__device__ __forceinline__ unsigned short f2bf(float f) {  // RTNE (init path only)
    unsigned int u = __float_as_uint(f);
    u += 0x7fffu + ((u >> 16) & 1u);
    return (unsigned short)(u >> 16);
}
__device__ __forceinline__ float bf2f(int u) {
    return __uint_as_float(((unsigned int)(u & 0xffff)) << 16);
}
__device__ __forceinline__ unsigned int pk2bf(float a, float b) {  // [lo=a, hi=b]
    union { __hip_bfloat162 h2; unsigned int u; } c;
    c.h2 = __float22bfloat162_rn(float2{a, b});
    return c.u;
}
__device__ __forceinline__ float tanh_fast(float x) {
    float e = exp2f(x * 2.8853900817779268f);
    return 1.0f - 2.0f * __builtin_amdgcn_rcpf(e + 1.0f);
}

__global__ __launch_bounds__(256, 4)
void narx_kernel(const float* __restrict__ x,
                 const float* __restrict__ Win,
                 const float* __restrict__ bin_g,
                 const float* __restrict__ Wxh,
                 const float* __restrict__ Whh,
                 const float* __restrict__ bh_g,
                 const float* __restrict__ Wout,
                 const float* __restrict__ bout_g,
                 float* __restrict__ out)
{
    __shared__ unsigned short s_u[GBLK * STR];   // u acts; doubles as weight staging in init
    __shared__ unsigned short s_h[GBLK * STR];   // h acts
    unsigned short* s_wT = s_u;                  // init-phase alias (4600 < 9216 shorts)

    const int tid   = threadIdx.x;
    const int w     = tid >> 6;
    const int lane  = tid & 63;
    const int lm    = lane & 15;
    const int q     = lane >> 4;
    const int G0    = blockIdx.x * GBLK;
    const int tt0   = blockIdx.y * TTB;
    const int wrow0 = w * 32;

    // zero the t<DLAG head of the output (poisoned before every launch)
    if (blockIdx.y == 0 && tid < GBLK) {
        #pragma unroll
        for (int t2 = 0; t2 < DLAG; ++t2)
            out[t2 * NG + G0 + tid] = 0.0f;
    }

    // ---- stage weights transposed (fp32 -> bf16), hoist A-frags to regs ----
    short8 wxhf[4][2], whhf[4][2], winf[4];
    {   // Wxh^T : s_wT[n*STR+k] = bf16(Wxh[k*64+n])
        int k = tid >> 2, n0 = (tid & 3) * 16;
        const float* src = Wxh + k * HIDN + n0;
        #pragma unroll
        for (int i = 0; i < 16; ++i) s_wT[(n0 + i) * STR + k] = f2bf(src[i]);
    }
    __syncthreads();
    #pragma unroll
    for (int tn = 0; tn < 4; ++tn)
        #pragma unroll
        for (int kk = 0; kk < 2; ++kk)
            wxhf[tn][kk] = *(const short8*)&s_wT[(tn*16 + lm) * STR + kk*32 + q*8];
    __syncthreads();
    {   // Whh^T
        int k = tid >> 2, n0 = (tid & 3) * 16;
        const float* src = Whh + k * HIDN + n0;
        #pragma unroll
        for (int i = 0; i < 16; ++i) s_wT[(n0 + i) * STR + k] = f2bf(src[i]);
    }
    __syncthreads();
    #pragma unroll
    for (int tn = 0; tn < 4; ++tn)
        #pragma unroll
        for (int kk = 0; kk < 2; ++kk)
            whhf[tn][kk] = *(const short8*)&s_wT[(tn*16 + lm) * STR + kk*32 + q*8];
    __syncthreads();
    {   // Win^T (16 x 64 -> [n][k], k<16)
        int k = tid >> 4, n0 = (tid & 15) * 4;
        const float* src = Win + k * HIDN + n0;
        #pragma unroll
        for (int i = 0; i < 4; ++i) s_wT[(n0 + i) * STR + k] = f2bf(src[i]);
    }
    __syncthreads();
    #pragma unroll
    for (int tn = 0; tn < 4; ++tn) {
        short8 z = {0,0,0,0,0,0,0,0};
        if (q < 2) z = *(const short8*)&s_wT[(tn*16 + lm) * STR + q*8];
        winf[tn] = z;   // quads 2,3 are K=16..31 zero-padding
    }

    // biases, fp32 exact, per-lane: index n' = tj*16 + q*4 + r
    float binf[4][4], bhf[4][4];
    #pragma unroll
    for (int tj = 0; tj < 4; ++tj) {
        f32x4 b4 = *(const f32x4*)&bin_g[tj*16 + q*4];
        f32x4 h4 = *(const f32x4*)&bh_g[tj*16 + q*4];
        #pragma unroll
        for (int r = 0; r < 4; ++r) { binf[tj][r] = b4[r]; bhf[tj][r] = h4[r]; }
    }
    const float boutf = bout_g[0];
    __syncthreads();   // last init barrier: staging alias dies, s_u becomes act buffer

    for (int ti = 0; ti < TTB; ++ti) {
        const int tt = tt0 + ti;

        for (int d = 0; d < DLAG; ++d) {
            // ---- u^T = Win^T . x^T  (+b_in, relu) ----
            f32x4 ua[4][2];
            #pragma unroll
            for (int tj = 0; tj < 4; ++tj)
                #pragma unroll
                for (int mt = 0; mt < 2; ++mt) {
                    f32x4 a;
                    a[0]=binf[tj][0]; a[1]=binf[tj][1]; a[2]=binf[tj][2]; a[3]=binf[tj][3];
                    ua[tj][mt] = a;
                }
            short8 xf[2];
            #pragma unroll
            for (int mt = 0; mt < 2; ++mt) {
                short8 z = {0,0,0,0,0,0,0,0};
                if (q < 2) {  // k = q*8.. <16 real, quads 2,3 zero-pad
                    const float* px =
                        x + ((size_t)(tt + d) * NG + (G0 + wrow0 + mt*16 + lm)) * NXF + q*8;
                    f32x4 a = *(const f32x4*)px;
                    f32x4 b = *(const f32x4*)(px + 4);
                    i32x4 xi;
                    xi[0] = (int)pk2bf(a[0], a[1]);
                    xi[1] = (int)pk2bf(a[2], a[3]);
                    xi[2] = (int)pk2bf(b[0], b[1]);
                    xi[3] = (int)pk2bf(b[2], b[3]);
                    z = __builtin_bit_cast(short8, xi);
                }
                xf[mt] = z;
            }
            #pragma unroll
            for (int tj = 0; tj < 4; ++tj)
                #pragma unroll
                for (int mt = 0; mt < 2; ++mt)
                    ua[tj][mt] = __builtin_amdgcn_mfma_f32_16x16x32_bf16(
                        winf[tj], xf[mt], ua[tj][mt], 0, 0, 0);
            // relu + packed cvt: lane holds u[n'=tj*16+q*4+r][m=lm], store act[m][n']
            #pragma unroll
            for (int tj = 0; tj < 4; ++tj)
                #pragma unroll
                for (int mt = 0; mt < 2; ++mt) {
                    u32x2 p;
                    p[0] = pk2bf(fmaxf(ua[tj][mt][0], 0.f), fmaxf(ua[tj][mt][1], 0.f));
                    p[1] = pk2bf(fmaxf(ua[tj][mt][2], 0.f), fmaxf(ua[tj][mt][3], 0.f));
                    *(u32x2*)&s_u[(wrow0 + mt*16 + lm) * STR + tj*16 + q*4] = p;
                }
            // (no barrier: s_u rows wrow0..wrow0+31 are wave-private)

            // ---- h^T = Wxh^T.u^T + Whh^T.h^T (+b_h, tanh) ----
            f32x4 ha[4][2];
            #pragma unroll
            for (int tn = 0; tn < 4; ++tn)
                #pragma unroll
                for (int mt = 0; mt < 2; ++mt) {
                    f32x4 a;
                    a[0]=bhf[tn][0]; a[1]=bhf[tn][1]; a[2]=bhf[tn][2]; a[3]=bhf[tn][3];
                    ha[tn][mt] = a;
                }
            #pragma unroll
            for (int kk = 0; kk < 2; ++kk) {
                short8 uf[2], hf[2];
                #pragma unroll
                for (int mt = 0; mt < 2; ++mt)
                    uf[mt] = *(const short8*)&s_u[(wrow0 + mt*16 + lm) * STR + kk*32 + q*8];
                if (d > 0) {
                    #pragma unroll
                    for (int mt = 0; mt < 2; ++mt)
                        hf[mt] = *(const short8*)&s_h[(wrow0 + mt*16 + lm) * STR + kk*32 + q*8];
                }
                #pragma unroll
                for (int tn = 0; tn < 4; ++tn)
                    #pragma unroll
                    for (int mt = 0; mt < 2; ++mt) {
                        ha[tn][mt] = __builtin_amdgcn_mfma_f32_16x16x32_bf16(
                            wxhf[tn][kk], uf[mt], ha[tn][mt], 0, 0, 0);
                        if (d > 0)
                            ha[tn][mt] = __builtin_amdgcn_mfma_f32_16x16x32_bf16(
                                whhf[tn][kk], hf[mt], ha[tn][mt], 0, 0, 0);
                    }
            }
            #pragma unroll
            for (int tn = 0; tn < 4; ++tn)
                #pragma unroll
                for (int mt = 0; mt < 2; ++mt) {
                    u32x2 p;
                    p[0] = pk2bf(tanh_fast(ha[tn][mt][0]), tanh_fast(ha[tn][mt][1]));
                    p[1] = pk2bf(tanh_fast(ha[tn][mt][2]), tanh_fast(ha[tn][mt][3]));
                    *(u32x2*)&s_h[(wrow0 + mt*16 + lm) * STR + tn*16 + q*4] = p;
                }
            // (no barrier: s_h rows are wave-private)
        }

        // ---- y = h @ Wout + bout : 2 lanes per row, fp32 Wout, fp32 store ----
        {
            int row = lane >> 1, half = lane & 1;
            const unsigned short* hr = &s_h[(wrow0 + row) * STR + half*32];
            const float* wo = Wout + half*32;
            float acc = 0.f;
            #pragma unroll
            for (int jb = 0; jb < 4; ++jb) {
                short8 hv = *(const short8*)&hr[jb*8];
                f32x4 w0 = *(const f32x4*)&wo[jb*8];
                f32x4 w1 = *(const f32x4*)&wo[jb*8 + 4];
                #pragma unroll
                for (int e = 0; e < 4; ++e)
                    acc += bf2f(hv[e]) * w0[e] + bf2f(hv[4+e]) * w1[e];
            }
            acc += __shfl_xor(acc, 1, 64);
            if (half == 0)
                out[(size_t)(tt + DLAG) * NG + G0 + wrow0 + row] = acc + boutf;
        }
        // (no barrier: next ti's writes are to this wave's own rows)
    }
}

extern "C" void kernel_launch(void* const* d_in, const int* in_sizes, int n_in,
                              void* d_out, int out_size, void* d_ws, size_t ws_size,
                              hipStream_t stream) {
    const float* x    = (const float*)d_in[0];
    const float* Win  = (const float*)d_in[1];
    const float* bin  = (const float*)d_in[2];
    const float* Wxh  = (const float*)d_in[3];
    const float* Whh  = (const float*)d_in[4];
    const float* bh   = (const float*)d_in[5];
    const float* Wout = (const float*)d_in[6];
    const float* bout = (const float*)d_in[7];
    float* out = (float*)d_out;

    dim3 grid(NG / GBLK, TOUTN / TTB);  // (16, 127)
    narx_kernel<<<grid, dim3(256), 0, stream>>>(x, Win, bin, Wxh, Whh, bh, Wout, bout, out);
}

// Round 8
// 279.419 us; speedup vs baseline: 2.2708x; 2.2708x over previous
//
#include <hip/hip_runtime.h>
#include <hip/hip_bf16.h>

// NARX RNN. Inputs fp32, compute bf16 MFMA 16x16x32, output fp32.
// Transposed GEMMs (Ht[n][m] = W^T . act^T): weight A-frags in regs, C/D
// packs straight into the [m][hid] LDS layout the next B-frag read wants.
// Register diet (R6 post-mortem: ~180 total regs -> 2 waves/EU was the
// limiter; forcing 4 waves/EU spilled): sequential mt tiles keep only 4
// f32x4 accumulators live; cap at 3 waves/EU (~170 regs) via launch_bounds.
// Main-loop LDS is wave-private -> no __syncthreads in the hot loop.

#define NTT   512
#define NG    2048
#define NXF   16
#define HIDN  64
#define DLAG  4
#define TOUTN 508
#define GBLK  128   // g rows per block (4 waves x 32)
#define TTB   4     // tt values per block
#define STR   72    // LDS row stride in shorts

typedef short  s16x8 __attribute__((ext_vector_type(8)));
typedef float  f32x4 __attribute__((ext_vector_type(4)));
typedef int    i32x4 __attribute__((ext_vector_type(4)));
typedef unsigned int u32x2 __attribute__((ext_vector_type(2)));

__device__ __forceinline__ unsigned short f2bf(float f) {  // RTNE (init path only)
    unsigned int u = __float_as_uint(f);
    u += 0x7fffu + ((u >> 16) & 1u);
    return (unsigned short)(u >> 16);
}
__device__ __forceinline__ float bf2f(int u) {
    return __uint_as_float(((unsigned int)(u & 0xffff)) << 16);
}
__device__ __forceinline__ unsigned int pk2bf(float a, float b) {  // [lo=a, hi=b]
    union { __hip_bfloat162 h2; unsigned int u; } c;
    c.h2 = __float22bfloat162_rn(float2{a, b});
    return c.u;
}
__device__ __forceinline__ float tanh_fast(float x) {
    float e = exp2f(x * 2.8853900817779268f);
    return 1.0f - 2.0f * __builtin_amdgcn_rcpf(e + 1.0f);
}

__global__ __launch_bounds__(256, 3)
void narx_kernel(const float* __restrict__ x,
                 const float* __restrict__ Win,
                 const float* __restrict__ bin_g,
                 const float* __restrict__ Wxh,
                 const float* __restrict__ Whh,
                 const float* __restrict__ bh_g,
                 const float* __restrict__ Wout,
                 const float* __restrict__ bout_g,
                 float* __restrict__ out)
{
    __shared__ unsigned short s_u[GBLK * STR];   // u acts; doubles as weight staging in init
    __shared__ unsigned short s_h[GBLK * STR];   // h acts
    unsigned short* s_wT = s_u;                  // init-phase alias

    const int tid   = threadIdx.x;
    const int w     = tid >> 6;
    const int lane  = tid & 63;
    const int lm    = lane & 15;
    const int q     = lane >> 4;
    const int G0    = blockIdx.x * GBLK;
    const int tt0   = blockIdx.y * TTB;
    const int wrow0 = w * 32;

    // zero the t<DLAG head of the output (poisoned before every launch)
    if (blockIdx.y == 0 && tid < GBLK) {
        #pragma unroll
        for (int t2 = 0; t2 < DLAG; ++t2)
            out[t2 * NG + G0 + tid] = 0.0f;
    }

    // ---- stage weights transposed (fp32 -> bf16), hoist A-frags to regs ----
    s16x8 wxhf[4][2], whhf[4][2], winf[4];
    {   // Wxh^T : s_wT[n*STR+k] = bf16(Wxh[k*64+n])
        int k = tid >> 2, n0 = (tid & 3) * 16;
        const float* src = Wxh + k * HIDN + n0;
        #pragma unroll
        for (int i = 0; i < 16; ++i) s_wT[(n0 + i) * STR + k] = f2bf(src[i]);
    }
    __syncthreads();
    #pragma unroll
    for (int tn = 0; tn < 4; ++tn)
        #pragma unroll
        for (int kk = 0; kk < 2; ++kk)
            wxhf[tn][kk] = *(const s16x8*)&s_wT[(tn*16 + lm) * STR + kk*32 + q*8];
    __syncthreads();
    {   // Whh^T
        int k = tid >> 2, n0 = (tid & 3) * 16;
        const float* src = Whh + k * HIDN + n0;
        #pragma unroll
        for (int i = 0; i < 16; ++i) s_wT[(n0 + i) * STR + k] = f2bf(src[i]);
    }
    __syncthreads();
    #pragma unroll
    for (int tn = 0; tn < 4; ++tn)
        #pragma unroll
        for (int kk = 0; kk < 2; ++kk)
            whhf[tn][kk] = *(const s16x8*)&s_wT[(tn*16 + lm) * STR + kk*32 + q*8];
    __syncthreads();
    {   // Win^T (16 x 64 -> [n][k], k<16)
        int k = tid >> 4, n0 = (tid & 15) * 4;
        const float* src = Win + k * HIDN + n0;
        #pragma unroll
        for (int i = 0; i < 4; ++i) s_wT[(n0 + i) * STR + k] = f2bf(src[i]);
    }
    __syncthreads();
    #pragma unroll
    for (int tj = 0; tj < 4; ++tj) {
        s16x8 z = {0,0,0,0,0,0,0,0};
        if (q < 2) z = *(const s16x8*)&s_wT[(tj*16 + lm) * STR + q*8];
        winf[tj] = z;   // quads 2,3 are K=16..31 zero-padding
    }

    // biases, fp32 exact, per-lane: index n' = tj*16 + q*4 + r
    float binf[4][4], bhf[4][4];
    #pragma unroll
    for (int tj = 0; tj < 4; ++tj) {
        f32x4 b4 = *(const f32x4*)&bin_g[tj*16 + q*4];
        f32x4 h4 = *(const f32x4*)&bh_g[tj*16 + q*4];
        #pragma unroll
        for (int r = 0; r < 4; ++r) { binf[tj][r] = b4[r]; bhf[tj][r] = h4[r]; }
    }
    const float boutf = bout_g[0];
    __syncthreads();   // staging alias dies, s_u becomes act buffer

    for (int ti = 0; ti < TTB; ++ti) {
        const int tt = tt0 + ti;

        for (int d = 0; d < DLAG; ++d) {
            // ---- u^T = Win^T . x^T  (+b_in, relu), one mt tile at a time ----
            #pragma unroll
            for (int mt = 0; mt < 2; ++mt) {
                s16x8 xf = {0,0,0,0,0,0,0,0};
                if (q < 2) {  // k = q*8.. <16 real, quads 2,3 zero-pad
                    const float* px =
                        x + ((size_t)(tt + d) * NG + (G0 + wrow0 + mt*16 + lm)) * NXF + q*8;
                    f32x4 a = *(const f32x4*)px;
                    f32x4 b = *(const f32x4*)(px + 4);
                    i32x4 xi;
                    xi[0] = (int)pk2bf(a[0], a[1]);
                    xi[1] = (int)pk2bf(a[2], a[3]);
                    xi[2] = (int)pk2bf(b[0], b[1]);
                    xi[3] = (int)pk2bf(b[2], b[3]);
                    xf = __builtin_bit_cast(s16x8, xi);
                }

                f32x4 ua[4];
                #pragma unroll
                for (int tj = 0; tj < 4; ++tj) {
                    f32x4 c;
                    c[0]=binf[tj][0]; c[1]=binf[tj][1]; c[2]=binf[tj][2]; c[3]=binf[tj][3];
                    ua[tj] = __builtin_amdgcn_mfma_f32_16x16x32_bf16(
                        winf[tj], xf, c, 0, 0, 0);
                }
                #pragma unroll
                for (int tj = 0; tj < 4; ++tj) {
                    u32x2 p;
                    p[0] = pk2bf(fmaxf(ua[tj][0], 0.f), fmaxf(ua[tj][1], 0.f));
                    p[1] = pk2bf(fmaxf(ua[tj][2], 0.f), fmaxf(ua[tj][3], 0.f));
                    *(u32x2*)&s_u[(wrow0 + mt*16 + lm) * STR + tj*16 + q*4] = p;
                }
            }
            // (no barrier: rows are wave-private)

            // ---- h^T = Wxh^T.u^T + Whh^T.h^T (+b_h, tanh), per mt tile ----
            #pragma unroll
            for (int mt = 0; mt < 2; ++mt) {
                f32x4 ha[4];
                #pragma unroll
                for (int tn = 0; tn < 4; ++tn) {
                    f32x4 c;
                    c[0]=bhf[tn][0]; c[1]=bhf[tn][1]; c[2]=bhf[tn][2]; c[3]=bhf[tn][3];
                    ha[tn] = c;
                }
                #pragma unroll
                for (int kk = 0; kk < 2; ++kk) {
                    s16x8 uf = *(const s16x8*)&s_u[(wrow0 + mt*16 + lm) * STR + kk*32 + q*8];
                    #pragma unroll
                    for (int tn = 0; tn < 4; ++tn)
                        ha[tn] = __builtin_amdgcn_mfma_f32_16x16x32_bf16(
                            wxhf[tn][kk], uf, ha[tn], 0, 0, 0);
                    if (d > 0) {
                        s16x8 hf = *(const s16x8*)&s_h[(wrow0 + mt*16 + lm) * STR + kk*32 + q*8];
                        #pragma unroll
                        for (int tn = 0; tn < 4; ++tn)
                            ha[tn] = __builtin_amdgcn_mfma_f32_16x16x32_bf16(
                                whhf[tn][kk], hf, ha[tn], 0, 0, 0);
                    }
                }
                #pragma unroll
                for (int tn = 0; tn < 4; ++tn) {
                    u32x2 p;
                    p[0] = pk2bf(tanh_fast(ha[tn][0]), tanh_fast(ha[tn][1]));
                    p[1] = pk2bf(tanh_fast(ha[tn][2]), tanh_fast(ha[tn][3]));
                    *(u32x2*)&s_h[(wrow0 + mt*16 + lm) * STR + tn*16 + q*4] = p;
                }
            }
            // (no barrier: rows are wave-private)
        }

        // ---- y = h @ Wout + bout : 2 lanes per row, fp32 Wout, fp32 store ----
        {
            int row = lane >> 1, half = lane & 1;
            const unsigned short* hr = &s_h[(wrow0 + row) * STR + half*32];
            const float* wo = Wout + half*32;
            float acc = 0.f;
            #pragma unroll
            for (int jb = 0; jb < 4; ++jb) {
                s16x8 hv = *(const s16x8*)&hr[jb*8];
                f32x4 w0 = *(const f32x4*)&wo[jb*8];
                f32x4 w1 = *(const f32x4*)&wo[jb*8 + 4];
                #pragma unroll
                for (int e = 0; e < 4; ++e)
                    acc += bf2f(hv[e]) * w0[e] + bf2f(hv[4+e]) * w1[e];
            }
            acc += __shfl_xor(acc, 1, 64);
            if (half == 0)
                out[(size_t)(tt + DLAG) * NG + G0 + wrow0 + row] = acc + boutf;
        }
        // (no barrier: next ti's writes are to this wave's own rows)
    }
}

extern "C" void kernel_launch(void* const* d_in, const int* in_sizes, int n_in,
                              void* d_out, int out_size, void* d_ws, size_t ws_size,
                              hipStream_t stream) {
    const float* x    = (const float*)d_in[0];
    const float* Win  = (const float*)d_in[1];
    const float* bin  = (const float*)d_in[2];
    const float* Wxh  = (const float*)d_in[3];
    const float* Whh  = (const float*)d_in[4];
    const float* bh   = (const float*)d_in[5];
    const float* Wout = (const float*)d_in[6];
    const float* bout = (const float*)d_in[7];
    float* out = (float*)d_out;

    dim3 grid(NG / GBLK, TOUTN / TTB);  // (16, 127)
    narx_kernel<<<grid, dim3(256), 0, stream>>>(x, Win, bin, Wxh, Whh, bh, Wout, bout, out);
}

// Round 9
// 246.075 us; speedup vs baseline: 2.5786x; 1.1355x over previous
//
#include <hip/hip_runtime.h>
#include <hip/hip_bf16.h>

// NARX RNN. Inputs fp32, compute bf16 MFMA 16x16x32, output fp32.
// Transposed GEMMs (Ht[n][m] = W^T . act^T); weight A-frags in regs.
// Key changes this round:
//  - u(s) ring: u depends only on s=tt+d; keep 4 LDS slices, compute each
//    distinct s once (7/block instead of 16) -> -56% u work.
//  - scale-fold 2*log2(e) into Wxh/Whh/bh at staging: tanh loses its mul.
//  - GBLK=64 (16 rows/wave, no mt loop) + b_in reloaded from L1 per slice:
//    ~145 live regs -> launch_bounds(256,3) without spill (R6/R8 spilled).
// LDS stride 68 shorts (136B): b128 frag reads 2-way conflict (free).
// Main-loop LDS is wave-private -> no __syncthreads in the hot loop.

#define NTT   512
#define NG    2048
#define NXF   16
#define HIDN  64
#define DLAG  4
#define TOUTN 508
#define GBLK  64    // g rows per block (4 waves x 16)
#define TTB   4     // tt values per block
#define STR   68    // LDS row stride in shorts
#define SCALE 2.8853900817779268f   // 2*log2(e)

typedef short  s16x8 __attribute__((ext_vector_type(8)));
typedef float  f32x4 __attribute__((ext_vector_type(4)));
typedef int    i32x4 __attribute__((ext_vector_type(4)));
typedef unsigned int u32x2 __attribute__((ext_vector_type(2)));

__device__ __forceinline__ unsigned short f2bf(float f) {  // RTNE (init only)
    unsigned int u = __float_as_uint(f);
    u += 0x7fffu + ((u >> 16) & 1u);
    return (unsigned short)(u >> 16);
}
__device__ __forceinline__ float bf2f(int u) {
    return __uint_as_float(((unsigned int)(u & 0xffff)) << 16);
}
__device__ __forceinline__ unsigned int pk2bf(float a, float b) {  // [lo=a, hi=b]
    union { __hip_bfloat162 h2; unsigned int u; } c;
    c.h2 = __float22bfloat162_rn(float2{a, b});
    return c.u;
}
__device__ __forceinline__ float tanh_pre(float a) {
    // a is already scaled by 2*log2(e) (folded into weights/bias)
    float e = exp2f(a);
    return fmaf(-2.0f, __builtin_amdgcn_rcpf(e + 1.0f), 1.0f);
}

__global__ __launch_bounds__(256, 3)
void narx_kernel(const float* __restrict__ x,
                 const float* __restrict__ Win,
                 const float* __restrict__ bin_g,
                 const float* __restrict__ Wxh,
                 const float* __restrict__ Whh,
                 const float* __restrict__ bh_g,
                 const float* __restrict__ Wout,
                 const float* __restrict__ bout_g,
                 float* __restrict__ out)
{
    __shared__ unsigned short s_u[4 * GBLK * STR];  // u ring, slot = s & 3
    __shared__ unsigned short s_h[GBLK * STR];      // h state
    unsigned short* s_wT = s_u;                     // init-phase alias

    const int tid   = threadIdx.x;
    const int w     = tid >> 6;
    const int lane  = tid & 63;
    const int lm    = lane & 15;
    const int q     = lane >> 4;
    const int G0    = blockIdx.x * GBLK;
    const int tt0   = blockIdx.y * TTB;
    const int wrow0 = w * 16;                       // this wave's 16 rows
    const int myrow = wrow0 + lm;                   // LDS row this lane serves

    // zero the t<DLAG head of the output (poisoned before every launch)
    if (blockIdx.y == 0 && tid < GBLK) {
        #pragma unroll
        for (int t2 = 0; t2 < DLAG; ++t2)
            out[t2 * NG + G0 + tid] = 0.0f;
    }

    // ---- stage weights transposed (fp32 -> bf16), hoist A-frags to regs ----
    s16x8 wxhf[4][2], whhf[4][2], winf[4];
    {   // Wxh^T scaled: s_wT[n*STR+k] = bf16(SCALE * Wxh[k*64+n])
        int k = tid >> 2, n0 = (tid & 3) * 16;
        const float* src = Wxh + k * HIDN + n0;
        #pragma unroll
        for (int i = 0; i < 16; ++i) s_wT[(n0 + i) * STR + k] = f2bf(src[i] * SCALE);
    }
    __syncthreads();
    #pragma unroll
    for (int tn = 0; tn < 4; ++tn)
        #pragma unroll
        for (int kk = 0; kk < 2; ++kk)
            wxhf[tn][kk] = *(const s16x8*)&s_wT[(tn*16 + lm) * STR + kk*32 + q*8];
    __syncthreads();
    {   // Whh^T scaled
        int k = tid >> 2, n0 = (tid & 3) * 16;
        const float* src = Whh + k * HIDN + n0;
        #pragma unroll
        for (int i = 0; i < 16; ++i) s_wT[(n0 + i) * STR + k] = f2bf(src[i] * SCALE);
    }
    __syncthreads();
    #pragma unroll
    for (int tn = 0; tn < 4; ++tn)
        #pragma unroll
        for (int kk = 0; kk < 2; ++kk)
            whhf[tn][kk] = *(const s16x8*)&s_wT[(tn*16 + lm) * STR + kk*32 + q*8];
    __syncthreads();
    {   // Win^T unscaled (16 x 64 -> [n][k], k<16)
        int k = tid >> 4, n0 = (tid & 15) * 4;
        const float* src = Win + k * HIDN + n0;
        #pragma unroll
        for (int i = 0; i < 4; ++i) s_wT[(n0 + i) * STR + k] = f2bf(src[i]);
    }
    __syncthreads();
    #pragma unroll
    for (int tj = 0; tj < 4; ++tj) {
        s16x8 z = {0,0,0,0,0,0,0,0};
        if (q < 2) z = *(const s16x8*)&s_wT[(tj*16 + lm) * STR + q*8];
        winf[tj] = z;   // quads 2,3 are K=16..31 zero-padding
    }

    // b_h (scaled), fp32, per-lane: index n' = tn*16 + q*4 + r
    float bhf[4][4];
    #pragma unroll
    for (int tn = 0; tn < 4; ++tn) {
        f32x4 h4 = *(const f32x4*)&bh_g[tn*16 + q*4];
        #pragma unroll
        for (int r = 0; r < 4; ++r) bhf[tn][r] = h4[r] * SCALE;
    }
    const float boutf = bout_g[0];
    __syncthreads();   // staging alias dies, s_u becomes the u ring

    for (int ti = 0; ti < TTB; ++ti) {
        const int tt = tt0 + ti;

        // ---- u ring maintenance: compute each distinct s exactly once ----
        const int sfirst = (ti == 0) ? tt0 : (tt + DLAG - 1);
        const int slast  = tt + DLAG - 1;
        for (int s = sfirst; s <= slast; ++s) {
            const int slot = s & 3;
            s16x8 xf = {0,0,0,0,0,0,0,0};
            if (q < 2) {  // k = q*8.. <16 real, quads 2,3 zero-pad
                const float* px = x + ((size_t)s * NG + (G0 + myrow)) * NXF + q*8;
                f32x4 a = *(const f32x4*)px;
                f32x4 b = *(const f32x4*)(px + 4);
                i32x4 xi;
                xi[0] = (int)pk2bf(a[0], a[1]);
                xi[1] = (int)pk2bf(a[2], a[3]);
                xi[2] = (int)pk2bf(b[0], b[1]);
                xi[3] = (int)pk2bf(b[2], b[3]);
                xf = __builtin_bit_cast(s16x8, xi);
            }
            #pragma unroll
            for (int tj = 0; tj < 4; ++tj) {
                f32x4 c = *(const f32x4*)&bin_g[tj*16 + q*4];   // L1-hot reload
                f32x4 ua = __builtin_amdgcn_mfma_f32_16x16x32_bf16(
                    winf[tj], xf, c, 0, 0, 0);
                u32x2 p;
                p[0] = pk2bf(fmaxf(ua[0], 0.f), fmaxf(ua[1], 0.f));
                p[1] = pk2bf(fmaxf(ua[2], 0.f), fmaxf(ua[3], 0.f));
                *(u32x2*)&s_u[(slot*GBLK + myrow) * STR + tj*16 + q*4] = p;
            }
        }
        // (no barrier: rows are wave-private)

        // ---- d-recurrence: h = tanh'(Wxh'.u + Whh'.h + bh') ----
        for (int d = 0; d < DLAG; ++d) {
            const int slot = (tt + d) & 3;
            f32x4 ha[4];
            #pragma unroll
            for (int tn = 0; tn < 4; ++tn) {
                f32x4 c;
                c[0]=bhf[tn][0]; c[1]=bhf[tn][1]; c[2]=bhf[tn][2]; c[3]=bhf[tn][3];
                ha[tn] = c;
            }
            #pragma unroll
            for (int kk = 0; kk < 2; ++kk) {
                s16x8 uf = *(const s16x8*)&s_u[(slot*GBLK + myrow) * STR + kk*32 + q*8];
                #pragma unroll
                for (int tn = 0; tn < 4; ++tn)
                    ha[tn] = __builtin_amdgcn_mfma_f32_16x16x32_bf16(
                        wxhf[tn][kk], uf, ha[tn], 0, 0, 0);
                if (d > 0) {
                    s16x8 hf = *(const s16x8*)&s_h[myrow * STR + kk*32 + q*8];
                    #pragma unroll
                    for (int tn = 0; tn < 4; ++tn)
                        ha[tn] = __builtin_amdgcn_mfma_f32_16x16x32_bf16(
                            whhf[tn][kk], hf, ha[tn], 0, 0, 0);
                }
            }
            #pragma unroll
            for (int tn = 0; tn < 4; ++tn) {
                u32x2 p;
                p[0] = pk2bf(tanh_pre(ha[tn][0]), tanh_pre(ha[tn][1]));
                p[1] = pk2bf(tanh_pre(ha[tn][2]), tanh_pre(ha[tn][3]));
                *(u32x2*)&s_h[myrow * STR + tn*16 + q*4] = p;
            }
            // (no barrier: rows are wave-private)
        }

        // ---- y = h @ Wout + bout : 4 lanes per row, fp32 Wout, fp32 store ----
        {
            int row = lane >> 2, part = lane & 3;
            const unsigned short* hr = &s_h[(wrow0 + row) * STR + part*16];
            const float* wo = Wout + part*16;
            float acc = 0.f;
            #pragma unroll
            for (int jb = 0; jb < 2; ++jb) {
                s16x8 hv = *(const s16x8*)&hr[jb*8];
                f32x4 w0 = *(const f32x4*)&wo[jb*8];
                f32x4 w1 = *(const f32x4*)&wo[jb*8 + 4];
                #pragma unroll
                for (int e = 0; e < 4; ++e)
                    acc += bf2f(hv[e]) * w0[e] + bf2f(hv[4+e]) * w1[e];
            }
            acc += __shfl_xor(acc, 1, 64);
            acc += __shfl_xor(acc, 2, 64);
            if (part == 0)
                out[(size_t)(tt + DLAG) * NG + G0 + wrow0 + row] = acc + boutf;
        }
        // (no barrier: next ti's writes are to this wave's own rows)
    }
}

extern "C" void kernel_launch(void* const* d_in, const int* in_sizes, int n_in,
                              void* d_out, int out_size, void* d_ws, size_t ws_size,
                              hipStream_t stream) {
    const float* x    = (const float*)d_in[0];
    const float* Win  = (const float*)d_in[1];
    const float* bin  = (const float*)d_in[2];
    const float* Wxh  = (const float*)d_in[3];
    const float* Whh  = (const float*)d_in[4];
    const float* bh   = (const float*)d_in[5];
    const float* Wout = (const float*)d_in[6];
    const float* bout = (const float*)d_in[7];
    float* out = (float*)d_out;

    dim3 grid(NG / GBLK, TOUTN / TTB);  // (32, 127)
    narx_kernel<<<grid, dim3(256), 0, stream>>>(x, Win, bin, Wxh, Whh, bh, Wout, bout, out);
}

// Round 11
// 230.267 us; speedup vs baseline: 2.7556x; 1.0686x over previous
//
#include <hip/hip_runtime.h>
#include <hip/hip_bf16.h>

// NARX RNN. Inputs fp32, compute bf16 MFMA 16x16x32, output fp32.
// ZERO-LDS hot loop via K-permuted weights (clean-room rewrite of R10):
//   C/D layout: lane (m=lane&15, q=lane>>4) holds rows 16tn+4q+r. Packing
//   pairs in natural order gives 16 bf16 elements where element e holds unit
//   16(e>>2)+4q+(e&3). Consuming elements [8kk..8kk+7] as the B-frag of the
//   kk-th K=32 MFMA places unit 32kk+psi(q,j) at assumed position 32kk+8q+j,
//   psi(q,j)=16(j>>2)+4q+(j&3). Staging Wxh^T/Whh^T with K permuted by
//   pi(p)= 32(p>>5)+16((p>>2)&1)+4((p>>3)&3)+(p&3) makes A hold the SAME
//   unit at the same position -> correct for any common A/B k-map.
//   u-ring (4 slots) and h live entirely in registers; no hot-loop LDS.
// s_win (resident Win^T) stride 32 with pad slots 16..31 zeroed: q>=2 frag
// reads hit exact zeros (paired with zero B) -- no garbage anywhere.
// tanh has 2*log2(e) folded into Wxh/Whh/bh (exp2-based, no mul).

#define NG    2048
#define NXF   16
#define HIDN  64
#define DLAG  4
#define TOUTN 508
#define GBLK  64    // g rows per block (4 waves x 16)
#define TTB   4     // tt values per block
#define STR   72    // staging stride (shorts)
#define SW    32    // resident Win^T stride (shorts)
#define SCALE 2.8853900817779268f   // 2*log2(e)

typedef short  s16x8 __attribute__((ext_vector_type(8)));
typedef float  f32x4 __attribute__((ext_vector_type(4)));
typedef unsigned int u32x4 __attribute__((ext_vector_type(4)));

__device__ __forceinline__ unsigned short f2bf(float f) {  // RTNE (init only)
    unsigned int u = __float_as_uint(f);
    u += 0x7fffu + ((u >> 16) & 1u);
    return (unsigned short)(u >> 16);
}
__device__ __forceinline__ unsigned int pk2bf(float a, float b) {  // [lo=a, hi=b]
    union { __hip_bfloat162 h2; unsigned int u; } c;
    c.h2 = __float22bfloat162_rn(float2{a, b});
    return c.u;
}
__device__ __forceinline__ float tanh_pre(float a) {
    // a is already scaled by 2*log2(e) (folded into weights/bias)
    float e = exp2f(a);
    return fmaf(-2.0f, __builtin_amdgcn_rcpf(e + 1.0f), 1.0f);
}

__global__ __launch_bounds__(256, 3)
void narx_kernel(const float* __restrict__ x,
                 const float* __restrict__ Win,
                 const float* __restrict__ bin_g,
                 const float* __restrict__ Wxh,
                 const float* __restrict__ Whh,
                 const float* __restrict__ bh_g,
                 const float* __restrict__ Wout,
                 const float* __restrict__ bout_g,
                 float* __restrict__ out)
{
    __shared__ unsigned short s_stage[HIDN * STR];  // transient weight staging
    __shared__ unsigned short s_win[HIDN * SW];     // resident Win^T, pad zeroed

    const int tid   = threadIdx.x;
    const int lane  = tid & 63;
    const int lm    = lane & 15;
    const int q     = lane >> 4;
    const int G0    = blockIdx.x * GBLK;
    const int tt0   = blockIdx.y * TTB;   // multiple of 4 -> slot = (ti+d)&3
    const int wrow0 = (tid >> 6) * 16;
    const int myg   = G0 + wrow0 + lm;

    // zero the t<DLAG head of the output (poisoned before every launch)
    if (blockIdx.y == 0 && tid < GBLK) {
        #pragma unroll
        for (int t2 = 0; t2 < DLAG; ++t2)
            out[t2 * NG + G0 + tid] = 0.0f;
    }

    // zero s_win pad slots 16..31 (disjoint from data slots 0..15: no race)
    {
        int r = tid >> 2, c0 = 16 + (tid & 3) * 4;
        #pragma unroll
        for (int i = 0; i < 4; ++i) s_win[r * SW + c0 + i] = 0;
    }

    // ---- stage Wxh^T / Whh^T with K permuted by pi, scaled; frags to regs ----
    const int p0  = tid >> 2;              // K-position this thread stages
    const int pi0 = 32*(p0>>5) + 16*((p0>>2)&1) + 4*((p0>>3)&3) + (p0&3);
    const int n0  = (tid & 3) * 16;

    s16x8 wxhf[4][2], whhf[4][2];
    {
        const float* src = Wxh + pi0 * HIDN + n0;
        #pragma unroll
        for (int i = 0; i < 16; ++i)
            s_stage[(n0 + i) * STR + p0] = f2bf(src[i] * SCALE);
    }
    __syncthreads();
    #pragma unroll
    for (int tn = 0; tn < 4; ++tn)
        #pragma unroll
        for (int kk = 0; kk < 2; ++kk)
            wxhf[tn][kk] = *(const s16x8*)&s_stage[(tn*16 + lm) * STR + kk*32 + q*8];
    __syncthreads();
    {
        const float* src = Whh + pi0 * HIDN + n0;
        #pragma unroll
        for (int i = 0; i < 16; ++i)
            s_stage[(n0 + i) * STR + p0] = f2bf(src[i] * SCALE);
    }
    __syncthreads();
    #pragma unroll
    for (int tn = 0; tn < 4; ++tn)
        #pragma unroll
        for (int kk = 0; kk < 2; ++kk)
            whhf[tn][kk] = *(const s16x8*)&s_stage[(tn*16 + lm) * STR + kk*32 + q*8];

    // ---- resident Win^T (unpermuted K = x features), slots k<16 ----
    {
        int k = tid >> 4, nn = (tid & 15) * 4;
        const float* src = Win + k * HIDN + nn;
        #pragma unroll
        for (int i = 0; i < 4; ++i) s_win[(nn + i) * SW + k] = f2bf(src[i]);
    }

    // b_h (scaled) fp32 per-lane: unit n = tn*16 + q*4 + r
    float bhf[4][4];
    #pragma unroll
    for (int tn = 0; tn < 4; ++tn) {
        f32x4 h4 = *(const f32x4*)&bh_g[tn*16 + q*4];
        #pragma unroll
        for (int r = 0; r < 4; ++r) bhf[tn][r] = h4[r] * SCALE;
    }
    const float boutf = bout_g[0];
    __syncthreads();   // s_win fully written; staging dead

    u32x4 ury[4][2];   // u ring: slot -> two packed B-frags (registers)

    auto do_slice = [&](const int s, const int slot) {
        s16x8 xf = {0,0,0,0,0,0,0,0};
        if (q < 2) {   // features k = q*8+j < 16; lanes q>=2 supply zeros
            const float* px = x + ((size_t)s * NG + myg) * NXF + q*8;
            f32x4 a = *(const f32x4*)px;
            f32x4 b = *(const f32x4*)(px + 4);
            u32x4 xi;
            xi[0] = pk2bf(a[0], a[1]);
            xi[1] = pk2bf(a[2], a[3]);
            xi[2] = pk2bf(b[0], b[1]);
            xi[3] = pk2bf(b[2], b[3]);
            xf = __builtin_bit_cast(s16x8, xi);
        }
        #pragma unroll
        for (int tj = 0; tj < 4; ++tj) {
            s16x8 wf = *(const s16x8*)&s_win[(tj*16 + lm) * SW + q*8];
            f32x4 c  = *(const f32x4*)&bin_g[tj*16 + q*4];
            f32x4 ua = __builtin_amdgcn_mfma_f32_16x16x32_bf16(wf, xf, c, 0, 0, 0);
            ury[slot][tj>>1][(tj&1)*2+0] = pk2bf(fmaxf(ua[0],0.f), fmaxf(ua[1],0.f));
            ury[slot][tj>>1][(tj&1)*2+1] = pk2bf(fmaxf(ua[2],0.f), fmaxf(ua[3],0.f));
        }
    };

    #pragma unroll
    for (int ti = 0; ti < TTB; ++ti) {
        const int tt = tt0 + ti;
        if (ti == 0) {
            #pragma unroll
            for (int k2 = 0; k2 < 4; ++k2) do_slice(tt0 + k2, k2);
        } else {
            do_slice(tt + DLAG - 1, (ti + DLAG - 1) & 3);
        }

        u32x4 hpv[2];   // packed h = next step's B-frags
        #pragma unroll
        for (int d = 0; d < DLAG; ++d) {
            const int slot = (ti + d) & 3;
            f32x4 ha[4];
            #pragma unroll
            for (int tn = 0; tn < 4; ++tn) {
                f32x4 c;
                c[0]=bhf[tn][0]; c[1]=bhf[tn][1]; c[2]=bhf[tn][2]; c[3]=bhf[tn][3];
                ha[tn] = c;
            }
            #pragma unroll
            for (int kk = 0; kk < 2; ++kk) {
                s16x8 uf = __builtin_bit_cast(s16x8, ury[slot][kk]);
                #pragma unroll
                for (int tn = 0; tn < 4; ++tn)
                    ha[tn] = __builtin_amdgcn_mfma_f32_16x16x32_bf16(
                        wxhf[tn][kk], uf, ha[tn], 0, 0, 0);
            }
            if (d > 0) {
                #pragma unroll
                for (int kk = 0; kk < 2; ++kk) {
                    s16x8 hf = __builtin_bit_cast(s16x8, hpv[kk]);
                    #pragma unroll
                    for (int tn = 0; tn < 4; ++tn)
                        ha[tn] = __builtin_amdgcn_mfma_f32_16x16x32_bf16(
                            whhf[tn][kk], hf, ha[tn], 0, 0, 0);
                }
            }
            float tv[4][4];
            #pragma unroll
            for (int tn = 0; tn < 4; ++tn)
                #pragma unroll
                for (int r = 0; r < 4; ++r)
                    tv[tn][r] = tanh_pre(ha[tn][r]);

            if (d < DLAG - 1) {
                #pragma unroll
                for (int tn = 0; tn < 4; ++tn) {
                    hpv[tn>>1][(tn&1)*2+0] = pk2bf(tv[tn][0], tv[tn][1]);
                    hpv[tn>>1][(tn&1)*2+1] = pk2bf(tv[tn][2], tv[tn][3]);
                }
            } else {
                // epilogue: y = Wout.h + bout (lane holds units 16tn+4q+r of col lm)
                float acc = 0.f;
                #pragma unroll
                for (int tn = 0; tn < 4; ++tn) {
                    f32x4 wo = *(const f32x4*)&Wout[tn*16 + q*4];
                    #pragma unroll
                    for (int r = 0; r < 4; ++r) acc += tv[tn][r] * wo[r];
                }
                acc += __shfl_xor(acc, 16, 64);
                acc += __shfl_xor(acc, 32, 64);
                if (lane < 16)
                    out[(size_t)(tt + DLAG) * NG + G0 + wrow0 + lane] = acc + boutf;
            }
        }
    }
}

extern "C" void kernel_launch(void* const* d_in, const int* in_sizes, int n_in,
                              void* d_out, int out_size, void* d_ws, size_t ws_size,
                              hipStream_t stream) {
    const float* x    = (const float*)d_in[0];
    const float* Win  = (const float*)d_in[1];
    const float* bin  = (const float*)d_in[2];
    const float* Wxh  = (const float*)d_in[3];
    const float* Whh  = (const float*)d_in[4];
    const float* bh   = (const float*)d_in[5];
    const float* Wout = (const float*)d_in[6];
    const float* bout = (const float*)d_in[7];
    float* out = (float*)d_out;

    dim3 grid(NG / GBLK, TOUTN / TTB);  // (32, 127)
    narx_kernel<<<grid, dim3(256), 0, stream>>>(x, Win, bin, Wxh, Whh, bh, Wout, bout, out);
}